// Round 5
// baseline (520.448 us; speedup 1.0000x reference)
//
#include <hip/hip_runtime.h>
#include <hip/hip_bf16.h>
#include <stdint.h>

// Problem constants (N=8192 rows, C=4096 classes; reduction dim of joint GEMM = N)
#define NROWS 8192
#define CDIM  4096
#define KDIM  8192
#define EPS   1e-12f

typedef __attribute__((ext_vector_type(8)))  int   v8i;     // 32 fp8 bytes (8 VGPRs)
typedef __attribute__((ext_vector_type(4)))  int   v4i;     // 16 fp8 bytes (4 VGPRs)
typedef __attribute__((ext_vector_type(4)))  float f32x4;
typedef __attribute__((ext_vector_type(2)))  float f32x2;

// Butterfly reductions: all lanes end with the result.
__device__ inline float wave_sum(float v) {
#pragma unroll
    for (int o = 32; o > 0; o >>= 1) v += __shfl_xor(v, o, 64);
    return v;
}
__device__ inline float wave_max(float v) {
#pragma unroll
    for (int o = 32; o > 0; o >>= 1) v = fmaxf(v, __shfl_xor(v, o, 64));
    return v;
}

// ---------------------------------------------------------------------------
// Pass 1: wave-per-row softmax stats + entropy + fp8 quantized row-major write.
// ---------------------------------------------------------------------------
__global__ __launch_bounds__(256) void row_quant_kernel(const float* __restrict__ X,
                                                        const float* __restrict__ Y,
                                                        unsigned char* __restrict__ QX,
                                                        unsigned char* __restrict__ QY,
                                                        float* __restrict__ entPart) {
    const int t = threadIdx.x, lane = t & 63, wave = t >> 6;
    const int row = blockIdx.x * 4 + wave;
    const bool isY = blockIdx.y != 0;
    const float4* s4 = (const float4*)((isY ? Y : X) + (size_t)row * CDIM);
    unsigned int* dst = (unsigned int*)((isY ? QY : QX) + (size_t)row * CDIM);
    float4 v[16];
#pragma unroll
    for (int i = 0; i < 16; i++) v[i] = s4[i * 64 + lane];
    float m = -3.0e38f;
#pragma unroll
    for (int i = 0; i < 16; i++)
        m = fmaxf(m, fmaxf(fmaxf(v[i].x, v[i].y), fmaxf(v[i].z, v[i].w)));
    m = wave_max(m);
    float Z = 0.f, S = 0.f;
#pragma unroll
    for (int i = 0; i < 16; i++) {
        float e;
        e = __expf(v[i].x - m); Z += e; S += e * v[i].x; v[i].x = e;
        e = __expf(v[i].y - m); Z += e; S += e * v[i].y; v[i].y = e;
        e = __expf(v[i].z - m); Z += e; S += e * v[i].z; v[i].z = e;
        e = __expf(v[i].w - m); Z += e; S += e * v[i].w; v[i].w = e;
    }
    Z = wave_sum(Z); S = wave_sum(S);
    __shared__ float sent[4];
    if (lane == 0) sent[wave] = m + __logf(Z) - S / Z;
    // quantize: q = fp8(512 * e / Z). 512*p_max ~ 4 << 448 (e4m3 max) -> safe.
    const float sc = 512.0f / Z;
#pragma unroll
    for (int i = 0; i < 16; i++) {
        unsigned int w0 = (unsigned int)__builtin_amdgcn_cvt_pk_fp8_f32(
            v[i].x * sc, v[i].y * sc, 0, false);
        w0 = (unsigned int)__builtin_amdgcn_cvt_pk_fp8_f32(
            v[i].z * sc, v[i].w * sc, (int)w0, true);
        dst[i * 64 + lane] = w0;   // 64 lanes x 4B contiguous = 256B/instr
    }
    __syncthreads();
    if (t == 0 && !isY)
        entPart[blockIdx.x] = sent[0] + sent[1] + sent[2] + sent[3];
}

// ---------------------------------------------------------------------------
// Pass 2: fp8 [N][C] -> [C][N] transpose, 128x128 byte tiles. v_perm 4x4 byte
// micro-transpose in registers -> XOR-swizzled LDS tile -> coalesced write-out.
// Margins (sum over n of dequantized fp8, per class) fused.
// ---------------------------------------------------------------------------
__global__ __launch_bounds__(256) void transpose_marg_kernel(
        const unsigned char* __restrict__ QX, const unsigned char* __restrict__ QY,
        unsigned char* __restrict__ QXT, unsigned char* __restrict__ QYT,
        float* __restrict__ margX, float* __restrict__ margY) {
    const bool isY = blockIdx.z != 0;
    const unsigned char* __restrict__ Q = isY ? QY : QX;
    unsigned char* __restrict__ QT = isY ? QYT : QXT;
    float* __restrict__ marg = isY ? margY : margX;

    __shared__ __align__(16) unsigned char tile[128 * 128];   // 16 KB transposed tile
    __shared__ float smarg[128];
    const int t = threadIdx.x;
    const int c0 = blockIdx.x * 128, n0 = blockIdx.y * 128;
    if (t < 128) smarg[t] = 0.f;
    __syncthreads();
    const int cq = (t & 31) * 4;   // class offset within tile (x4)
    const int nq = (t >> 5) * 16;  // n offset within tile (x16)
    const unsigned char* src = Q + (size_t)(n0 + nq) * CDIM + c0 + cq;
    unsigned int u[16];
#pragma unroll
    for (int i = 0; i < 16; i++)
        u[i] = *(const unsigned int*)(src + (size_t)i * CDIM);  // 2 rows x 128B per instr
    // 4x4 byte micro-transpose: d[j][k] = n-consecutive bytes for class cq+j
#pragma unroll
    for (int j = 0; j < 4; j++) {
        const unsigned int sel = (unsigned)j | ((unsigned)(j + 4) << 8);
        unsigned int d0, d1, d2, d3;
        {
            unsigned int p01 = __builtin_amdgcn_perm(u[1], u[0], sel);
            unsigned int p23 = __builtin_amdgcn_perm(u[3], u[2], sel);
            d0 = __builtin_amdgcn_perm(p23, p01, 0x05040100u);
        }
        {
            unsigned int p01 = __builtin_amdgcn_perm(u[5], u[4], sel);
            unsigned int p23 = __builtin_amdgcn_perm(u[7], u[6], sel);
            d1 = __builtin_amdgcn_perm(p23, p01, 0x05040100u);
        }
        {
            unsigned int p01 = __builtin_amdgcn_perm(u[9], u[8], sel);
            unsigned int p23 = __builtin_amdgcn_perm(u[11], u[10], sel);
            d2 = __builtin_amdgcn_perm(p23, p01, 0x05040100u);
        }
        {
            unsigned int p01 = __builtin_amdgcn_perm(u[13], u[12], sel);
            unsigned int p23 = __builtin_amdgcn_perm(u[15], u[14], sel);
            d3 = __builtin_amdgcn_perm(p23, p01, 0x05040100u);
        }
        const int r = cq + j;                        // out-row within tile
        // swizzled LDS write: logical unit nq>>4, physical unit ^ ((r>>2)&7)
        uint4 o; o.x = d0; o.y = d1; o.z = d2; o.w = d3;
        *(uint4*)&tile[r * 128 + ((((nq >> 4) ^ ((r >> 2) & 7))) << 4)] = o;
        // margin partial: dequant-sum the 16 fp8 values (same bytes GEMM reads)
        float s = 0.f;
        f32x2 a;
        a = __builtin_amdgcn_cvt_pk_f32_fp8((int)d0, false); s += a.x + a.y;
        a = __builtin_amdgcn_cvt_pk_f32_fp8((int)d0, true);  s += a.x + a.y;
        a = __builtin_amdgcn_cvt_pk_f32_fp8((int)d1, false); s += a.x + a.y;
        a = __builtin_amdgcn_cvt_pk_f32_fp8((int)d1, true);  s += a.x + a.y;
        a = __builtin_amdgcn_cvt_pk_f32_fp8((int)d2, false); s += a.x + a.y;
        a = __builtin_amdgcn_cvt_pk_f32_fp8((int)d2, true);  s += a.x + a.y;
        a = __builtin_amdgcn_cvt_pk_f32_fp8((int)d3, false); s += a.x + a.y;
        a = __builtin_amdgcn_cvt_pk_f32_fp8((int)d3, true);  s += a.x + a.y;
        atomicAdd(&smarg[r], s);
    }
    __syncthreads();
    // coalesced write-out: 4 rounds; lanes 0..7 emit one contiguous 128B row
#pragma unroll
    for (int p = 0; p < 4; p++) {
        const int r = p * 32 + (t >> 3);             // out-row within tile
        const int k = t & 7;                         // logical 16B unit
        uint4 o = *(const uint4*)&tile[r * 128 + (((k ^ ((r >> 2) & 7))) << 4)];
        *(uint4*)(QT + (size_t)(c0 + r) * KDIM + n0 + k * 16) = o;
    }
    if (t < 128) atomicAdd(&marg[c0 + t], smarg[t]);
}

// ---------------------------------------------------------------------------
// Pass 3 (R5: m201-faithful phase schedule): joint GEMM, MX-fp8 16x16x128,
// 256x256 tile, BK=128, 8 waves (2x4), wave-tile 128x64 (acc 8x4), dbuf
// 128 KiB LDS.  Each K-tile iter = 4 PHASES; phase p:
//   { 2 x GLD16 (pair p of tile t+1) ; ds_read af rows {2p,2p+1} (+bg in ph0)
//     ; s_barrier ; lgkmcnt(0) ; setprio(1) ; 8 MFMA ; setprio(0) ; s_barrier }
// Tile-ready wait = vmcnt(2) at ph0 (2 newest = just-issued next-tile pair;
// everything older = all of tile t -> done). Never drains to 0 in main loop.
// R4 post-mortem: pipes were SERIALIZED (iter = 5440 cy ~ MFMA 2208 + LDS
// ~2400 + VMEM ~1000; MfmaUtil 39% = exactly the MFMA floor). m196 isolated
// the per-phase interleave as the +28-41% lever; m201 = 62% MfmaUtil in this
// exact config. Per-entry MFMA K-order unchanged -> bit-identical output.
// ---------------------------------------------------------------------------
#define GLD16(g, l)                                                                   \
    __builtin_amdgcn_global_load_lds((const __attribute__((address_space(1))) unsigned int*)(g), \
                                     (__attribute__((address_space(3))) unsigned int*)(l), 16, 0, 0)

#define BUFSZ 65536   // one (A 32K + B 32K) tile pair
#define BOFS  32768   // B region offset within a buffer

__device__ __forceinline__ v8i pack8(const unsigned char* p, int off0, int off1) {
    v4i lo = *(const v4i*)(p + off0);
    v4i hi = *(const v4i*)(p + off1);
    v8i a;
    a[0] = lo[0]; a[1] = lo[1]; a[2] = lo[2]; a[3] = lo[3];
    a[4] = hi[0]; a[5] = hi[1]; a[6] = hi[2]; a[7] = hi[3];
    return a;
}

template <int P>
__device__ __forceinline__ void phase_mfma(const v8i& a0, const v8i& a1,
                                           const v8i (&bg)[4], f32x4 (&acc)[8][4]) {
    __builtin_amdgcn_s_setprio(1);
#pragma unroll
    for (int j = 0; j < 4; j++)
        acc[2 * P][j] = __builtin_amdgcn_mfma_scale_f32_16x16x128_f8f6f4(
            a0, bg[j], acc[2 * P][j], 0, 0, 0, 0x7f, 0, 0x7f);
#pragma unroll
    for (int j = 0; j < 4; j++)
        acc[2 * P + 1][j] = __builtin_amdgcn_mfma_scale_f32_16x16x128_f8f6f4(
            a1, bg[j], acc[2 * P + 1][j], 0, 0, 0, 0x7f, 0, 0x7f);
    __builtin_amdgcn_s_setprio(0);
}

__global__ __launch_bounds__(512, 2) void gemm_mi_kernel(const unsigned char* __restrict__ A,
                                                         const unsigned char* __restrict__ B,
                                                         float* __restrict__ S_out) {
    __shared__ __align__(16) unsigned char lds[131072];   // 2 x (32K A + 32K B)
    const int t = threadIdx.x;
    const int lane = t & 63, wave = t >> 6;
    const int m0 = blockIdx.x * 256, n0 = blockIdx.y * 256;

    // staging map: pair i of wave w fills rows [w*32+i*8, +8) x 128B linearly
    const int srow = wave * 32 + (lane >> 3);
    const int gcol = ((lane & 7) ^ (lane >> 3)) * 16;   // pre-swizzled source unit
    const unsigned char* ga = A + (size_t)(m0 + srow) * KDIM + gcol;
    const unsigned char* gb = B + (size_t)(n0 + srow) * KDIM + gcol;
    const int loff = wave * 4096 + lane * 16;            // linear LDS dest

    // fragment map: wave-tile 128x64 at (wm, wn); rows wm+i*16+fr
    const int wm = (wave >> 2) * 128, wn = (wave & 3) * 64;
    const int fr = lane & 15, quad = lane >> 4, sw = fr & 7;
    const int off0 = ((2 * quad)     ^ sw) * 16;
    const int off1 = ((2 * quad + 1) ^ sw) * 16;

    f32x4 acc[8][4];
#pragma unroll
    for (int i = 0; i < 8; i++)
#pragma unroll
        for (int j = 0; j < 4; j++) { acc[i][j][0] = 0.f; acc[i][j][1] = 0.f; acc[i][j][2] = 0.f; acc[i][j][3] = 0.f; }

    // prologue: stage tile 0 into buffer 0 (8 loads)
#pragma unroll
    for (int i = 0; i < 4; i++) {
        GLD16(ga + (size_t)i * 8 * KDIM, lds + loff + i * 1024);
        GLD16(gb + (size_t)i * 8 * KDIM, lds + BOFS + loff + i * 1024);
    }

    int cur = 0;
    for (int tt = 0; tt < KDIM / 128; ++tt) {
        const unsigned char* base = lds + cur * BUFSZ;
        unsigned char* nbuf = lds + (cur ^ 1) * BUFSZ;
        const size_t kn = (size_t)(tt + 1) * 128;
        const bool more = (tt + 1 < KDIM / 128);

        // ================= phase 0 =================
        if (more) {
            GLD16(ga + kn, nbuf + loff);
            GLD16(gb + kn, nbuf + BOFS + loff);
            asm volatile("s_waitcnt vmcnt(2)" ::: "memory");   // tile t done; pair0 of t+1 in flight
        } else {
            asm volatile("s_waitcnt vmcnt(0)" ::: "memory");   // final drain
        }
        asm volatile("s_barrier" ::: "memory");                // tile t ready for all waves
        __builtin_amdgcn_sched_barrier(0);
        v8i bg[4];
#pragma unroll
        for (int j = 0; j < 4; j++)
            bg[j] = pack8(base + BOFS + (wn + j * 16 + fr) * 128, off0, off1);
        {
            v8i a0 = pack8(base + (wm + 0 * 16 + fr) * 128, off0, off1);
            v8i a1 = pack8(base + (wm + 1 * 16 + fr) * 128, off0, off1);
            asm volatile("s_barrier" ::: "memory");
            asm volatile("s_waitcnt lgkmcnt(0)" ::: "memory");
            __builtin_amdgcn_sched_barrier(0);
            phase_mfma<0>(a0, a1, bg, acc);
        }
        asm volatile("s_barrier" ::: "memory");
        __builtin_amdgcn_sched_barrier(0);

        // ================= phase 1 =================
        if (more) {
            GLD16(ga + (size_t)8 * KDIM + kn, nbuf + loff + 1024);
            GLD16(gb + (size_t)8 * KDIM + kn, nbuf + BOFS + loff + 1024);
        }
        {
            v8i a0 = pack8(base + (wm + 2 * 16 + fr) * 128, off0, off1);
            v8i a1 = pack8(base + (wm + 3 * 16 + fr) * 128, off0, off1);
            asm volatile("s_barrier" ::: "memory");
            asm volatile("s_waitcnt lgkmcnt(0)" ::: "memory");
            __builtin_amdgcn_sched_barrier(0);
            phase_mfma<1>(a0, a1, bg, acc);
        }
        asm volatile("s_barrier" ::: "memory");
        __builtin_amdgcn_sched_barrier(0);

        // ================= phase 2 =================
        if (more) {
            GLD16(ga + (size_t)16 * KDIM + kn, nbuf + loff + 2048);
            GLD16(gb + (size_t)16 * KDIM + kn, nbuf + BOFS + loff + 2048);
        }
        {
            v8i a0 = pack8(base + (wm + 4 * 16 + fr) * 128, off0, off1);
            v8i a1 = pack8(base + (wm + 5 * 16 + fr) * 128, off0, off1);
            asm volatile("s_barrier" ::: "memory");
            asm volatile("s_waitcnt lgkmcnt(0)" ::: "memory");
            __builtin_amdgcn_sched_barrier(0);
            phase_mfma<2>(a0, a1, bg, acc);
        }
        asm volatile("s_barrier" ::: "memory");
        __builtin_amdgcn_sched_barrier(0);

        // ================= phase 3 =================
        if (more) {
            GLD16(ga + (size_t)24 * KDIM + kn, nbuf + loff + 3072);
            GLD16(gb + (size_t)24 * KDIM + kn, nbuf + BOFS + loff + 3072);
        }
        {
            v8i a0 = pack8(base + (wm + 6 * 16 + fr) * 128, off0, off1);
            v8i a1 = pack8(base + (wm + 7 * 16 + fr) * 128, off0, off1);
            asm volatile("s_barrier" ::: "memory");
            asm volatile("s_waitcnt lgkmcnt(0)" ::: "memory");
            __builtin_amdgcn_sched_barrier(0);
            phase_mfma<3>(a0, a1, bg, acc);
        }
        // closing: my LDS reads are consumed; barrier -> buf `base` free for t+2
        asm volatile("s_waitcnt lgkmcnt(0)" ::: "memory");
        asm volatile("s_barrier" ::: "memory");
        __builtin_amdgcn_sched_barrier(0);
        cur ^= 1;
    }

    // epilogue: acc = 512^2 * N * joint -> joint = acc * 2^-31. Global sum.
    const float invS = 4.656612873077393e-10f;   // 2^-31
    float loc = 0.f;
#pragma unroll
    for (int i = 0; i < 8; i++)
#pragma unroll
        for (int j = 0; j < 4; j++)
#pragma unroll
            for (int r = 0; r < 4; r++) {
                float v = acc[i][j][r] * invS;
                loc += v * __logf(v + EPS);
            }
    loc = wave_sum(loc);
    __shared__ float sred[8];
    if (lane == 0) sred[wave] = loc;
    __syncthreads();
    if (t == 0) {
        float s = 0.f;
#pragma unroll
        for (int w = 0; w < 8; w++) s += sred[w];
        atomicAdd(S_out, s);
    }
}

// ---------------------------------------------------------------------------
// Pass 4: finalize. entropy = sum entPart / N;
// MI = S_jlogj - sum mX log(mX+eps) - sum mY log(mY+eps); marg scale 2^-22.
// ---------------------------------------------------------------------------
__global__ __launch_bounds__(256) void finalize_kernel(const float* __restrict__ accums,
                                                       const float* __restrict__ entPart,
                                                       const float* __restrict__ margX,
                                                       const float* __restrict__ margY,
                                                       float* __restrict__ out) {
    const int t = threadIdx.x;
    const int lane = t & 63, w = t >> 6;
    const float invN = 1.0f / 8192.0f;
    const float invM = 1.0f / 4194304.0f;   // 1/(512*8192) = 2^-22
    float sx = 0.f, sy = 0.f, se = 0.f;
    for (int c = t; c < CDIM; c += 256) {
        float mx = margX[c] * invM;
        float my = margY[c] * invM;
        sx += mx * __logf(mx + EPS);
        sy += my * __logf(my + EPS);
    }
    for (int c = t; c < 2048; c += 256) se += entPart[c];
    sx = wave_sum(sx); sy = wave_sum(sy); se = wave_sum(se);
    __shared__ float rx[4], ry[4], re[4];
    if (lane == 0) { rx[w] = sx; ry[w] = sy; re[w] = se; }
    __syncthreads();
    if (t == 0) {
        float SX = rx[0] + rx[1] + rx[2] + rx[3];
        float SY = ry[0] + ry[1] + ry[2] + ry[3];
        float SE = re[0] + re[1] + re[2] + re[3];
        out[0] = SE * invN;                 // mean entropy
        out[1] = accums[0] - SX - SY;       // MI
    }
}

// ---------------------------------------------------------------------------
// Workspace layout (bytes):
//   0          QX   fp8 [8192][4096]   33554432   (row-major probs x512)
//   33554432   QY   fp8 [8192][4096]   33554432
//   67108864   QXT  fp8 [4096][8192]   33554432   (transposed, GEMM operand)
//   100663296  QYT  fp8 [4096][8192]   33554432
//   134217728  margX f32[4096]            16384
//   134234112  margY f32[4096]            16384
//   134250496  accums f32[0]=S_jlogj        256
//   134250752  entPart f32[2048]           8192
// ---------------------------------------------------------------------------
extern "C" void kernel_launch(void* const* d_in, const int* in_sizes, int n_in,
                              void* d_out, int out_size, void* d_ws, size_t ws_size,
                              hipStream_t stream) {
    const float* X = (const float*)d_in[0];
    const float* Y = (const float*)d_in[1];
    char* ws = (char*)d_ws;
    unsigned char* QX  = (unsigned char*)ws;
    unsigned char* QY  = (unsigned char*)(ws + 33554432ll);
    unsigned char* QXT = (unsigned char*)(ws + 67108864ll);
    unsigned char* QYT = (unsigned char*)(ws + 100663296ll);
    float* margX = (float*)(ws + 134217728ll);
    float* margY = (float*)(ws + 134234112ll);
    float* accums = (float*)(ws + 134250496ll);
    float* entPart = (float*)(ws + 134250752ll);

    // zero margins + accumulators (ws is poisoned 0xAA before every launch)
    hipMemsetAsync(ws + 134217728ll, 0, 2 * 16384 + 256, stream);

    row_quant_kernel<<<dim3(2048, 2), 256, 0, stream>>>(X, Y, QX, QY, entPart);
    transpose_marg_kernel<<<dim3(CDIM / 128, NROWS / 128, 2), 256, 0, stream>>>(
        QX, QY, QXT, QYT, margX, margY);
    gemm_mi_kernel<<<dim3(CDIM / 256, CDIM / 256), 512, 0, stream>>>(QXT, QYT, &accums[0]);
    finalize_kernel<<<1, 256, 0, stream>>>(accums, entPart, margX, margY, (float*)d_out);
}

// Round 6
// 457.989 us; speedup vs baseline: 1.1364x; 1.1364x over previous
//
#include <hip/hip_runtime.h>
#include <hip/hip_bf16.h>
#include <stdint.h>

// Problem constants (N=8192 rows, C=4096 classes; reduction dim of joint GEMM = N)
#define NROWS 8192
#define CDIM  4096
#define KDIM  8192
#define EPS   1e-12f

typedef __attribute__((ext_vector_type(8)))  int   v8i;     // 32 fp8 bytes (8 VGPRs)
typedef __attribute__((ext_vector_type(4)))  int   v4i;     // 16 fp8 bytes (4 VGPRs)
typedef __attribute__((ext_vector_type(4)))  float f32x4;
typedef __attribute__((ext_vector_type(2)))  float f32x2;

// Butterfly reductions: all lanes end with the result.
__device__ inline float wave_sum(float v) {
#pragma unroll
    for (int o = 32; o > 0; o >>= 1) v += __shfl_xor(v, o, 64);
    return v;
}
__device__ inline float wave_max(float v) {
#pragma unroll
    for (int o = 32; o > 0; o >>= 1) v = fmaxf(v, __shfl_xor(v, o, 64));
    return v;
}

// ---------------------------------------------------------------------------
// Pass 1: wave-per-row softmax stats + entropy + fp8 quantized row-major write.
// R6: block (0,0) also zeroes margX/margY/accums (33 KB contiguous), replacing
// the serial hipMemsetAsync at the stream head (completes before transpose's
// atomics by stream order).
// ---------------------------------------------------------------------------
__global__ __launch_bounds__(256) void row_quant_kernel(const float* __restrict__ X,
                                                        const float* __restrict__ Y,
                                                        unsigned char* __restrict__ QX,
                                                        unsigned char* __restrict__ QY,
                                                        float* __restrict__ entPart,
                                                        float* __restrict__ zbase) {
    const int t = threadIdx.x, lane = t & 63, wave = t >> 6;
    if (blockIdx.x == 0 && blockIdx.y == 0) {
        // zero margX[4096] + margY[4096] + accums[64] = 8256 contiguous floats
        for (int i = t; i < 8256; i += 256) zbase[i] = 0.f;
    }
    const int row = blockIdx.x * 4 + wave;
    const bool isY = blockIdx.y != 0;
    const float4* s4 = (const float4*)((isY ? Y : X) + (size_t)row * CDIM);
    unsigned int* dst = (unsigned int*)((isY ? QY : QX) + (size_t)row * CDIM);
    float4 v[16];
#pragma unroll
    for (int i = 0; i < 16; i++) v[i] = s4[i * 64 + lane];
    float m = -3.0e38f;
#pragma unroll
    for (int i = 0; i < 16; i++)
        m = fmaxf(m, fmaxf(fmaxf(v[i].x, v[i].y), fmaxf(v[i].z, v[i].w)));
    m = wave_max(m);
    float Z = 0.f, S = 0.f;
#pragma unroll
    for (int i = 0; i < 16; i++) {
        float e;
        e = __expf(v[i].x - m); Z += e; S += e * v[i].x; v[i].x = e;
        e = __expf(v[i].y - m); Z += e; S += e * v[i].y; v[i].y = e;
        e = __expf(v[i].z - m); Z += e; S += e * v[i].z; v[i].z = e;
        e = __expf(v[i].w - m); Z += e; S += e * v[i].w; v[i].w = e;
    }
    Z = wave_sum(Z); S = wave_sum(S);
    __shared__ float sent[4];
    if (lane == 0) sent[wave] = m + __logf(Z) - S / Z;
    // quantize: q = fp8(512 * e / Z). 512*p_max ~ 4 << 448 (e4m3 max) -> safe.
    const float sc = 512.0f / Z;
#pragma unroll
    for (int i = 0; i < 16; i++) {
        unsigned int w0 = (unsigned int)__builtin_amdgcn_cvt_pk_fp8_f32(
            v[i].x * sc, v[i].y * sc, 0, false);
        w0 = (unsigned int)__builtin_amdgcn_cvt_pk_fp8_f32(
            v[i].z * sc, v[i].w * sc, (int)w0, true);
        dst[i * 64 + lane] = w0;   // 64 lanes x 4B contiguous = 256B/instr
    }
    __syncthreads();
    if (t == 0 && !isY)
        entPart[blockIdx.x] = sent[0] + sent[1] + sent[2] + sent[3];
}

// ---------------------------------------------------------------------------
// Pass 2: fp8 [N][C] -> [C][N] transpose, 128x128 byte tiles. v_perm 4x4 byte
// micro-transpose in registers -> XOR-swizzled LDS tile -> coalesced write-out.
// Margins (sum over n of dequantized fp8, per class) fused.
// ---------------------------------------------------------------------------
__global__ __launch_bounds__(256) void transpose_marg_kernel(
        const unsigned char* __restrict__ QX, const unsigned char* __restrict__ QY,
        unsigned char* __restrict__ QXT, unsigned char* __restrict__ QYT,
        float* __restrict__ margX, float* __restrict__ margY) {
    const bool isY = blockIdx.z != 0;
    const unsigned char* __restrict__ Q = isY ? QY : QX;
    unsigned char* __restrict__ QT = isY ? QYT : QXT;
    float* __restrict__ marg = isY ? margY : margX;

    __shared__ __align__(16) unsigned char tile[128 * 128];   // 16 KB transposed tile
    __shared__ float smarg[128];
    const int t = threadIdx.x;
    const int c0 = blockIdx.x * 128, n0 = blockIdx.y * 128;
    if (t < 128) smarg[t] = 0.f;
    __syncthreads();
    const int cq = (t & 31) * 4;   // class offset within tile (x4)
    const int nq = (t >> 5) * 16;  // n offset within tile (x16)
    const unsigned char* src = Q + (size_t)(n0 + nq) * CDIM + c0 + cq;
    unsigned int u[16];
#pragma unroll
    for (int i = 0; i < 16; i++)
        u[i] = *(const unsigned int*)(src + (size_t)i * CDIM);  // 2 rows x 128B per instr
    // 4x4 byte micro-transpose: d[j][k] = n-consecutive bytes for class cq+j
#pragma unroll
    for (int j = 0; j < 4; j++) {
        const unsigned int sel = (unsigned)j | ((unsigned)(j + 4) << 8);
        unsigned int d0, d1, d2, d3;
        {
            unsigned int p01 = __builtin_amdgcn_perm(u[1], u[0], sel);
            unsigned int p23 = __builtin_amdgcn_perm(u[3], u[2], sel);
            d0 = __builtin_amdgcn_perm(p23, p01, 0x05040100u);
        }
        {
            unsigned int p01 = __builtin_amdgcn_perm(u[5], u[4], sel);
            unsigned int p23 = __builtin_amdgcn_perm(u[7], u[6], sel);
            d1 = __builtin_amdgcn_perm(p23, p01, 0x05040100u);
        }
        {
            unsigned int p01 = __builtin_amdgcn_perm(u[9], u[8], sel);
            unsigned int p23 = __builtin_amdgcn_perm(u[11], u[10], sel);
            d2 = __builtin_amdgcn_perm(p23, p01, 0x05040100u);
        }
        {
            unsigned int p01 = __builtin_amdgcn_perm(u[13], u[12], sel);
            unsigned int p23 = __builtin_amdgcn_perm(u[15], u[14], sel);
            d3 = __builtin_amdgcn_perm(p23, p01, 0x05040100u);
        }
        const int r = cq + j;                        // out-row within tile
        // swizzled LDS write: logical unit nq>>4, physical unit ^ ((r>>2)&7)
        uint4 o; o.x = d0; o.y = d1; o.z = d2; o.w = d3;
        *(uint4*)&tile[r * 128 + ((((nq >> 4) ^ ((r >> 2) & 7))) << 4)] = o;
        // margin partial: dequant-sum the 16 fp8 values (same bytes GEMM reads)
        float s = 0.f;
        f32x2 a;
        a = __builtin_amdgcn_cvt_pk_f32_fp8((int)d0, false); s += a.x + a.y;
        a = __builtin_amdgcn_cvt_pk_f32_fp8((int)d0, true);  s += a.x + a.y;
        a = __builtin_amdgcn_cvt_pk_f32_fp8((int)d1, false); s += a.x + a.y;
        a = __builtin_amdgcn_cvt_pk_f32_fp8((int)d1, true);  s += a.x + a.y;
        a = __builtin_amdgcn_cvt_pk_f32_fp8((int)d2, false); s += a.x + a.y;
        a = __builtin_amdgcn_cvt_pk_f32_fp8((int)d2, true);  s += a.x + a.y;
        a = __builtin_amdgcn_cvt_pk_f32_fp8((int)d3, false); s += a.x + a.y;
        a = __builtin_amdgcn_cvt_pk_f32_fp8((int)d3, true);  s += a.x + a.y;
        atomicAdd(&smarg[r], s);
    }
    __syncthreads();
    // coalesced write-out: 4 rounds; lanes 0..7 emit one contiguous 128B row
#pragma unroll
    for (int p = 0; p < 4; p++) {
        const int r = p * 32 + (t >> 3);             // out-row within tile
        const int k = t & 7;                         // logical 16B unit
        uint4 o = *(const uint4*)&tile[r * 128 + (((k ^ ((r >> 2) & 7))) << 4)];
        *(uint4*)(QT + (size_t)(c0 + r) * KDIM + n0 + k * 16) = o;
    }
    if (t < 128) atomicAdd(&marg[c0 + t], smarg[t]);
}

// ---------------------------------------------------------------------------
// Pass 3 (R6 = exact R4 revert, measured 145 us / MfmaUtil 39%): joint GEMM,
// MX-fp8 16x16x128, 256x256 tile, BK=128, 8 waves (2x4), wave-tile 128x64
// (acc 8x4), double-buffered 128 KiB LDS, monolithic compute block per K-tile
// with COUNTED vmcnt(8) across raw s_barrier (loads issued a FULL iteration
// before their wait -> latency fully hidden; R5's phase split shortened that
// distance to ~1 phase and regressed 45%). lgkmcnt(0) before the closing
// barrier closes the buffer-overwrite race. T5 setprio around MFMA cluster.
// Fragment rule identical for A and B; epilogue is a permutation-invariant
// global sum -> layout errors cancel; per-entry MFMA K-order fixed ->
// bit-identical result (absmax 0.01146221).
// Structure note: depth-2 prefetch needs 192 KB LDS (doesn't exist) and the
// BK=64 ring alternative forces >=4-way LDS conflicts (64B rows) -> this
// 2-barrier monolith is the structural optimum at this LDS budget.
// ---------------------------------------------------------------------------
#define GLD16(g, l)                                                                   \
    __builtin_amdgcn_global_load_lds((const __attribute__((address_space(1))) unsigned int*)(g), \
                                     (__attribute__((address_space(3))) unsigned int*)(l), 16, 0, 0)

#define BUFSZ 65536   // one (A 32K + B 32K) tile pair
#define BOFS  32768   // B region offset within a buffer

__global__ __launch_bounds__(512, 2) void gemm_mi_kernel(const unsigned char* __restrict__ A,
                                                         const unsigned char* __restrict__ B,
                                                         float* __restrict__ S_out) {
    __shared__ __align__(16) unsigned char lds[131072];   // 2 x (32K A + 32K B)
    const int t = threadIdx.x;
    const int lane = t & 63, wave = t >> 6;
    const int m0 = blockIdx.x * 256, n0 = blockIdx.y * 256;

    // staging map: pair i of wave w fills rows [w*32+i*8, +8) x 128B linearly
    const int srow = wave * 32 + (lane >> 3);
    const int gcol = ((lane & 7) ^ (lane >> 3)) * 16;   // pre-swizzled source unit
    const unsigned char* ga = A + (size_t)(m0 + srow) * KDIM + gcol;
    const unsigned char* gb = B + (size_t)(n0 + srow) * KDIM + gcol;
    const int loff = wave * 4096 + lane * 16;            // linear LDS dest

    // fragment map: wave-tile 128x64 at (wm, wn); rows wm+i*16+fr
    const int wm = (wave >> 2) * 128, wn = (wave & 3) * 64;
    const int fr = lane & 15, quad = lane >> 4, sw = fr & 7;
    const int off0 = ((2 * quad)     ^ sw) * 16;
    const int off1 = ((2 * quad + 1) ^ sw) * 16;

    f32x4 acc[8][4];
#pragma unroll
    for (int i = 0; i < 8; i++)
#pragma unroll
        for (int j = 0; j < 4; j++) { acc[i][j][0] = 0.f; acc[i][j][1] = 0.f; acc[i][j][2] = 0.f; acc[i][j][3] = 0.f; }

    // prologue: stage tile 0 into buffer 0
#pragma unroll
    for (int i = 0; i < 4; i++) {
        GLD16(ga + (size_t)i * 8 * KDIM, lds + loff + i * 1024);
        GLD16(gb + (size_t)i * 8 * KDIM, lds + BOFS + loff + i * 1024);
    }

    int cur = 0;
    for (int tt = 0; tt < KDIM / 128; ++tt) {
        if (tt + 1 < KDIM / 128) {
            const int nb = (cur ^ 1) * BUFSZ;
            const int kn = (tt + 1) * 128;
#pragma unroll
            for (int i = 0; i < 4; i++) {
                GLD16(ga + (size_t)i * 8 * KDIM + kn, lds + nb + loff + i * 1024);
                GLD16(gb + (size_t)i * 8 * KDIM + kn, lds + nb + BOFS + loff + i * 1024);
            }
            // wait only the CURRENT tile's 8 loads; next tile's 8 stay in flight
            asm volatile("s_waitcnt vmcnt(8)" ::: "memory");
        } else {
            asm volatile("s_waitcnt vmcnt(0)" ::: "memory");
        }
        asm volatile("s_barrier" ::: "memory");           // tile tt ready for all waves
        __builtin_amdgcn_sched_barrier(0);

        const unsigned char* base = lds + cur * BUFSZ;
        v8i bg[4];
#pragma unroll
        for (int j = 0; j < 4; j++) {
            const unsigned char* pB = base + BOFS + (wn + j * 16 + fr) * 128;
            v4i lo = *(const v4i*)(pB + off0);
            v4i hi = *(const v4i*)(pB + off1);
            bg[j][0] = lo[0]; bg[j][1] = lo[1]; bg[j][2] = lo[2]; bg[j][3] = lo[3];
            bg[j][4] = hi[0]; bg[j][5] = hi[1]; bg[j][6] = hi[2]; bg[j][7] = hi[3];
        }
        __builtin_amdgcn_s_setprio(1);
#pragma unroll
        for (int i = 0; i < 8; i++) {
            const unsigned char* pA = base + (wm + i * 16 + fr) * 128;
            v4i lo = *(const v4i*)(pA + off0);
            v4i hi = *(const v4i*)(pA + off1);
            v8i af;
            af[0] = lo[0]; af[1] = lo[1]; af[2] = lo[2]; af[3] = lo[3];
            af[4] = hi[0]; af[5] = hi[1]; af[6] = hi[2]; af[7] = hi[3];
#pragma unroll
            for (int j = 0; j < 4; j++)
                acc[i][j] = __builtin_amdgcn_mfma_scale_f32_16x16x128_f8f6f4(
                    af, bg[j], acc[i][j], 0 /*A=fp8*/, 0 /*B=fp8*/,
                    0, 0x7f /*scaleA e8m0=1.0*/, 0, 0x7f /*scaleB*/);
        }
        __builtin_amdgcn_s_setprio(0);
        __builtin_amdgcn_sched_barrier(0);
        // drain my LDS reads, then barrier: after this, others may overwrite cur
        asm volatile("s_waitcnt lgkmcnt(0)" ::: "memory");
        asm volatile("s_barrier" ::: "memory");
        __builtin_amdgcn_sched_barrier(0);
        cur ^= 1;
    }

    // epilogue: acc = 512^2 * N * joint -> joint = acc * 2^-31. Global sum.
    const float invS = 4.656612873077393e-10f;   // 2^-31
    float loc = 0.f;
#pragma unroll
    for (int i = 0; i < 8; i++)
#pragma unroll
        for (int j = 0; j < 4; j++)
#pragma unroll
            for (int r = 0; r < 4; r++) {
                float v = acc[i][j][r] * invS;
                loc += v * __logf(v + EPS);
            }
    loc = wave_sum(loc);
    __shared__ float sred[8];
    if (lane == 0) sred[wave] = loc;
    __syncthreads();
    if (t == 0) {
        float s = 0.f;
#pragma unroll
        for (int w = 0; w < 8; w++) s += sred[w];
        atomicAdd(S_out, s);
    }
}

// ---------------------------------------------------------------------------
// Pass 4: finalize. entropy = sum entPart / N;
// MI = S_jlogj - sum mX log(mX+eps) - sum mY log(mY+eps); marg scale 2^-22.
// ---------------------------------------------------------------------------
__global__ __launch_bounds__(256) void finalize_kernel(const float* __restrict__ accums,
                                                       const float* __restrict__ entPart,
                                                       const float* __restrict__ margX,
                                                       const float* __restrict__ margY,
                                                       float* __restrict__ out) {
    const int t = threadIdx.x;
    const int lane = t & 63, w = t >> 6;
    const float invN = 1.0f / 8192.0f;
    const float invM = 1.0f / 4194304.0f;   // 1/(512*8192) = 2^-22
    float sx = 0.f, sy = 0.f, se = 0.f;
    for (int c = t; c < CDIM; c += 256) {
        float mx = margX[c] * invM;
        float my = margY[c] * invM;
        sx += mx * __logf(mx + EPS);
        sy += my * __logf(my + EPS);
    }
    for (int c = t; c < 2048; c += 256) se += entPart[c];
    sx = wave_sum(sx); sy = wave_sum(sy); se = wave_sum(se);
    __shared__ float rx[4], ry[4], re[4];
    if (lane == 0) { rx[w] = sx; ry[w] = sy; re[w] = se; }
    __syncthreads();
    if (t == 0) {
        float SX = rx[0] + rx[1] + rx[2] + rx[3];
        float SY = ry[0] + ry[1] + ry[2] + ry[3];
        float SE = re[0] + re[1] + re[2] + re[3];
        out[0] = SE * invN;                 // mean entropy
        out[1] = accums[0] - SX - SY;       // MI
    }
}

// ---------------------------------------------------------------------------
// Workspace layout (bytes):
//   0          QX   fp8 [8192][4096]   33554432   (row-major probs x512)
//   33554432   QY   fp8 [8192][4096]   33554432
//   67108864   QXT  fp8 [4096][8192]   33554432   (transposed, GEMM operand)
//   100663296  QYT  fp8 [4096][8192]   33554432
//   134217728  margX f32[4096]            16384
//   134234112  margY f32[4096]            16384
//   134250496  accums f32[0]=S_jlogj        256
//   134250752  entPart f32[2048]           8192
// (margX..accums zeroed by row_quant block (0,0); entPart fully overwritten.)
// ---------------------------------------------------------------------------
extern "C" void kernel_launch(void* const* d_in, const int* in_sizes, int n_in,
                              void* d_out, int out_size, void* d_ws, size_t ws_size,
                              hipStream_t stream) {
    const float* X = (const float*)d_in[0];
    const float* Y = (const float*)d_in[1];
    char* ws = (char*)d_ws;
    unsigned char* QX  = (unsigned char*)ws;
    unsigned char* QY  = (unsigned char*)(ws + 33554432ll);
    unsigned char* QXT = (unsigned char*)(ws + 67108864ll);
    unsigned char* QYT = (unsigned char*)(ws + 100663296ll);
    float* margX = (float*)(ws + 134217728ll);
    float* margY = (float*)(ws + 134234112ll);
    float* accums = (float*)(ws + 134250496ll);
    float* entPart = (float*)(ws + 134250752ll);

    row_quant_kernel<<<dim3(2048, 2), 256, 0, stream>>>(X, Y, QX, QY, entPart, margX);
    transpose_marg_kernel<<<dim3(CDIM / 128, NROWS / 128, 2), 256, 0, stream>>>(
        QX, QY, QXT, QYT, margX, margY);
    gemm_mi_kernel<<<dim3(CDIM / 256, CDIM / 256), 512, 0, stream>>>(QXT, QYT, &accums[0]);
    finalize_kernel<<<1, 256, 0, stream>>>(accums, entPart, margX, margY, (float*)d_out);
}